// Round 2
// baseline (2787.021 us; speedup 1.0000x reference)
//
#include <hip/hip_runtime.h>

// QuantizerEncoder: code[n,h,w,m] = argmax_k < wq[m] @ q_raw[n,h,w,m], wk[m] @ cb[m,k] >
// n=16, d=512, h=64, w=64, m=4, kcodes=256, dm=128
//
// Round 1: identical to round 0 (fold Wq into keys -> keff[m,k,d]; fp64 dot + argmax),
// but write the code index as INT32 — the harness reads integer-dtype outputs via the
// np.int32 branch (round-0 absmax 1.13e9 == float bit pattern of 255.0 read as int32).

#define MM   4
#define KC   256
#define DM   128
#define HW   4096   // h*w = 64*64
#define NTOT 16
#define HH   64
#define WW_  64

// ---- Kernel 1: keys[m][k][c] = sum_d cb[m][k][d] * wk[m][c][d]  (fp64) ----
__global__ __launch_bounds__(128) void keys_kernel(const float* __restrict__ cb,
                                                   const float* __restrict__ wk,
                                                   double* __restrict__ keys) {
    int mk = blockIdx.x;          // m*256 + k, 0..1023
    int c  = threadIdx.x;         // 0..127
    int m  = mk >> 8;
    const float* cbr = cb + (size_t)mk * DM;               // cb[m][k][*]
    const float* wkr = wk + ((size_t)m * DM + c) * DM;     // wk[m][c][*]
    double s = 0.0;
    for (int d = 0; d < DM; ++d)
        s = fma((double)cbr[d], (double)wkr[d], s);
    keys[(size_t)mk * DM + c] = s;
}

// ---- Kernel 2: keff[m][k][d] = sum_c wq[m][c][d] * keys[m][k][c]  (fp64) ----
__global__ __launch_bounds__(128) void keff_kernel(const float* __restrict__ wq,
                                                   const double* __restrict__ keys,
                                                   double* __restrict__ keff) {
    int mk = blockIdx.x;          // m*256 + k
    int d  = threadIdx.x;         // 0..127
    int m  = mk >> 8;
    const double* kr  = keys + (size_t)mk * DM;            // keys[m][k][*]
    const float*  wqm = wq + (size_t)m * DM * DM;          // wq[m][c][d]
    double s = 0.0;
    for (int c = 0; c < DM; ++c)
        s = fma((double)wqm[(size_t)c * DM + d], kr[c], s);
    keff[(size_t)mk * DM + d] = s;
}

// ---- Kernel 3: per (pixel, group) argmax over 256 codes, fp64 dot ----
// block = 256 threads: w = tid&63 (lane dim, coalesced), m = tid>>6 (one wave per group)
// grid  = n*h = 1024 blocks
__global__ __launch_bounds__(256) void argmax_kernel(const float* __restrict__ latent,
                                                     const double* __restrict__ keff,
                                                     int* __restrict__ out) {
    int b   = blockIdx.x;            // n*64 + h
    int n   = b >> 6;
    int h   = b & 63;
    int tid = threadIdx.x;
    int w   = tid & 63;
    int m   = tid >> 6;
    // wave-uniform m so keff reads can become scalar loads
    int mu  = __builtin_amdgcn_readfirstlane(m);

    // load q_raw[128] for this (n,h,w,m): stride h*w between channels, lanes coalesced in w
    const float* lp = latent + ((size_t)n * 512 + (size_t)m * DM) * HW + (size_t)h * WW_ + w;
    float qr[DM];
#pragma unroll
    for (int d = 0; d < DM; ++d) qr[d] = lp[(size_t)d * HW];

    const double* kp = keff + (size_t)mu * KC * DM;

    double bestv = -1.0e300;
    int    best  = 0;
    for (int k = 0; k < KC; k += 4) {
        const double* r0 = kp + (size_t)k * DM;
        const double* r1 = r0 + DM;
        const double* r2 = r1 + DM;
        const double* r3 = r2 + DM;
        double s0 = 0.0, s1 = 0.0, s2 = 0.0, s3 = 0.0;
#pragma unroll
        for (int d = 0; d < DM; ++d) {
            double qd = (double)qr[d];
            s0 = fma(qd, r0[d], s0);
            s1 = fma(qd, r1[d], s1);
            s2 = fma(qd, r2[d], s2);
            s3 = fma(qd, r3[d], s3);
        }
        // ascending k + strict '>' == numpy first-occurrence argmax tie-break
        if (s0 > bestv) { bestv = s0; best = k;     }
        if (s1 > bestv) { bestv = s1; best = k + 1; }
        if (s2 > bestv) { bestv = s2; best = k + 2; }
        if (s3 > bestv) { bestv = s3; best = k + 3; }
    }

    // out[n][h][w][m], read back by harness as int32
    out[((size_t)b * WW_ + w) * MM + m] = best;
}

extern "C" void kernel_launch(void* const* d_in, const int* in_sizes, int n_in,
                              void* d_out, int out_size, void* d_ws, size_t ws_size,
                              hipStream_t stream) {
    const float* latent = (const float*)d_in[0];   // [16,512,64,64]
    const float* cb     = (const float*)d_in[1];   // [4,256,128]
    const float* wq     = (const float*)d_in[2];   // [4,128,128]
    const float* wk     = (const float*)d_in[3];   // [4,128,128]
    int* out = (int*)d_out;                        // 262144 code indices as int32

    // workspace: keys (1 MB fp64) | keff (1 MB fp64)
    double* keys = (double*)d_ws;
    double* keff = keys + (size_t)MM * KC * DM;

    keys_kernel<<<MM * KC, 128, 0, stream>>>(cb, wk, keys);
    keff_kernel<<<MM * KC, 128, 0, stream>>>(wq, keys, keff);
    argmax_kernel<<<NTOT * HH, 256, 0, stream>>>(latent, keff, out);
}

// Round 3
// 1177.840 us; speedup vs baseline: 2.3662x; 2.3662x over previous
//
#include <hip/hip_runtime.h>

// QuantizerEncoder: code[n,h,w,m] = argmax_k < wq[m] @ q_raw[n,h,w,m], wk[m] @ cb[m,k] >
// n=16, d=512, h=64, w=64, m=4, kcodes=256, dm=128
//
// Round 2: fp32 fast path + fp64 rescue of near-ties.
//   A[m]    = wk[m]^T @ wq[m]                       (fp64, 8.4M MAC, coalesced)
//   keff[m] = cb[m] @ A[m]                          (fp64 + fp32 copy, 16.8M MAC)
//   fast:   scores fp32, track best+second; gap < EPS -> worklist
//   rescue: fp64 full 256-dot argmax for flagged pixel-groups (expected ~0.3%)
// Final result is fp64-canonical for every pixel (EPS=1e-2 >> fp32 error ~1e-4).

#define MM   4
#define KC   256
#define DM   128
#define HW   4096   // h*w
#define NTOT 16
#define HH   64
#define WW_  64
#define EPS  1e-2f
#define WL_CAP 65536

// ---- Kernel 1: A[m][e][d] = sum_c wk[m][c][e] * wq[m][c][d]  (fp64) ----
// grid = m*128 (e), threads = d. wk read wave-uniform (scalar), wq coalesced in d.
__global__ __launch_bounds__(128) void a_kernel(const float* __restrict__ wk,
                                                const float* __restrict__ wq,
                                                double* __restrict__ A) {
    int me = blockIdx.x;           // m*128 + e
    int d  = threadIdx.x;
    int m  = me >> 7;
    int e  = me & 127;
    const float* wkm = wk + (size_t)m * DM * DM;   // wk[m][c][e]
    const float* wqm = wq + (size_t)m * DM * DM;   // wq[m][c][d]
    double s = 0.0;
    for (int c = 0; c < DM; ++c)
        s = fma((double)wkm[(size_t)c * DM + e], (double)wqm[(size_t)c * DM + d], s);
    A[(size_t)me * DM + d] = s;
}

// ---- Kernel 2: keff[m][k][d] = sum_e cb[m][k][e] * A[m][e][d]  (fp64 + fp32 copy) ----
// grid = m*256 (k), threads = d. cb wave-uniform (scalar), A coalesced in d.
__global__ __launch_bounds__(128) void keff_kernel(const float* __restrict__ cb,
                                                   const double* __restrict__ A,
                                                   double* __restrict__ keffd,
                                                   float* __restrict__ keff32) {
    int mk = blockIdx.x;           // m*256 + k
    int d  = threadIdx.x;
    int m  = mk >> 8;
    const float*  cbr = cb + (size_t)mk * DM;          // cb[m][k][*]
    const double* Am  = A + (size_t)m * DM * DM;       // A[m][e][d]
    double s = 0.0;
    for (int e = 0; e < DM; ++e)
        s = fma((double)cbr[e], Am[(size_t)e * DM + d], s);
    keffd[(size_t)mk * DM + d]  = s;
    keff32[(size_t)mk * DM + d] = (float)s;
}

// ---- Kernel 3: fp32 argmax with near-tie detection ----
// block = 256 threads: w = tid&63 (coalesced lane dim), m = tid>>6 (one wave per group)
// grid = n*h = 1024
__global__ __launch_bounds__(256, 3) void argmax_fast(const float* __restrict__ latent,
                                                      const float* __restrict__ keff32,
                                                      int* __restrict__ out,
                                                      int* __restrict__ wl_cnt,
                                                      int* __restrict__ wl) {
    int b   = blockIdx.x;            // n*64 + h
    int n   = b >> 6;
    int h   = b & 63;
    int tid = threadIdx.x;
    int w   = tid & 63;
    int m   = tid >> 6;
    int mu  = __builtin_amdgcn_readfirstlane(m);   // wave-uniform -> scalar keff loads

    const float* lp = latent + ((size_t)n * 512 + (size_t)m * DM) * HW + (size_t)h * WW_ + w;
    float qr[DM];
#pragma unroll
    for (int d = 0; d < DM; ++d) qr[d] = lp[(size_t)d * HW];

    const float* kp = keff32 + (size_t)mu * KC * DM;

    float bestv = -3.0e38f, secondv = -3.0e38f;
    int   best  = 0;
    for (int k = 0; k < KC; k += 4) {
        const float* r0 = kp + (size_t)k * DM;
        const float* r1 = r0 + DM;
        const float* r2 = r1 + DM;
        const float* r3 = r2 + DM;
        float s0 = 0.f, s1 = 0.f, s2 = 0.f, s3 = 0.f;
#pragma unroll
        for (int d = 0; d < DM; ++d) {
            float qd = qr[d];
            s0 = fmaf(qd, r0[d], s0);
            s1 = fmaf(qd, r1[d], s1);
            s2 = fmaf(qd, r2[d], s2);
            s3 = fmaf(qd, r3[d], s3);
        }
        // ascending k + strict '>' == first-occurrence argmax; track runner-up
        if (s0 > bestv) { secondv = bestv; bestv = s0; best = k;     } else if (s0 > secondv) secondv = s0;
        if (s1 > bestv) { secondv = bestv; bestv = s1; best = k + 1; } else if (s1 > secondv) secondv = s1;
        if (s2 > bestv) { secondv = bestv; bestv = s2; best = k + 2; } else if (s2 > secondv) secondv = s2;
        if (s3 > bestv) { secondv = bestv; bestv = s3; best = k + 3; } else if (s3 > secondv) secondv = s3;
    }

    int pix = ((b * WW_ + w) * MM) + m;   // n,h,w,m flat index
    out[pix] = best;

    if (bestv - secondv < EPS) {
        int slot = atomicAdd(wl_cnt, 1);
        if (slot < WL_CAP) wl[slot] = pix;
    }
}

// ---- Kernel 4: fp64 rescue of flagged pixel-groups ----
// 256 threads: thread k computes the fp64 dot for code k, then block argmax
// (ties -> lowest index, matching numpy first-occurrence).
__global__ __launch_bounds__(256) void rescue_kernel(const float* __restrict__ latent,
                                                     const double* __restrict__ keffd,
                                                     const int* __restrict__ wl_cnt,
                                                     const int* __restrict__ wl,
                                                     int* __restrict__ out) {
    __shared__ double svals[256];
    __shared__ int    sidx[256];
    int cnt = *wl_cnt;
    if (cnt > WL_CAP) cnt = WL_CAP;
    int t = threadIdx.x;
    for (int i = blockIdx.x; i < cnt; i += gridDim.x) {
        int pix = wl[i];
        int m   = pix & 3;
        int rem = pix >> 2;          // (n*64+h)*64 + w
        int w   = rem & 63;
        int bh  = rem >> 6;          // n*64+h
        int n   = bh >> 6;
        int h   = bh & 63;
        const float*  lp = latent + ((size_t)n * 512 + (size_t)m * DM) * HW + (size_t)h * WW_ + w;
        const double* kr = keffd + ((size_t)m * KC + t) * DM;
        double s = 0.0;
        for (int d = 0; d < DM; ++d)
            s = fma((double)lp[(size_t)d * HW], kr[d], s);
        svals[t] = s;
        sidx[t]  = t;
        __syncthreads();
        for (int stp = 128; stp > 0; stp >>= 1) {
            if (t < stp) {
                double vo = svals[t + stp], vm = svals[t];
                int io = sidx[t + stp], im = sidx[t];
                if (vo > vm || (vo == vm && io < im)) { svals[t] = vo; sidx[t] = io; }
            }
            __syncthreads();
        }
        if (t == 0) out[pix] = sidx[0];
        __syncthreads();
    }
}

extern "C" void kernel_launch(void* const* d_in, const int* in_sizes, int n_in,
                              void* d_out, int out_size, void* d_ws, size_t ws_size,
                              hipStream_t stream) {
    const float* latent = (const float*)d_in[0];   // [16,512,64,64]
    const float* cb     = (const float*)d_in[1];   // [4,256,128]
    const float* wq     = (const float*)d_in[2];   // [4,128,128]
    const float* wk     = (const float*)d_in[3];   // [4,128,128]
    int* out = (int*)d_out;                        // 262144 code indices (int32)

    // workspace layout
    char* ws = (char*)d_ws;
    double* A       = (double*)ws;                          ws += (size_t)MM * DM * DM * sizeof(double);   // 512 KB
    double* keffd   = (double*)ws;                          ws += (size_t)MM * KC * DM * sizeof(double);   // 1 MB
    float*  keff32  = (float*)ws;                           ws += (size_t)MM * KC * DM * sizeof(float);    // 512 KB
    int*    wl_cnt  = (int*)ws;                             ws += 256;
    int*    wl      = (int*)ws;                              // WL_CAP * 4 = 256 KB

    hipMemsetAsync(wl_cnt, 0, sizeof(int), stream);
    a_kernel<<<MM * DM, 128, 0, stream>>>(wk, wq, A);
    keff_kernel<<<MM * KC, 128, 0, stream>>>(cb, A, keffd, keff32);
    argmax_fast<<<NTOT * HH, 256, 0, stream>>>(latent, keff32, out, wl_cnt, wl);
    rescue_kernel<<<128, 256, 0, stream>>>(latent, keffd, wl_cnt, wl, out);
}

// Round 4
// 1132.406 us; speedup vs baseline: 2.4611x; 1.0401x over previous
//
#include <hip/hip_runtime.h>

// QuantizerEncoder: code[n,h,w,m] = argmax_k < wq[m] @ q_raw[n,h,w,m], wk[m] @ cb[m,k] >
// n=16, d=512, h=64, w=64, m=4, kcodes=256, dm=128
//
// Round 3: same algorithm as R2 (fold Wq into keys -> keff; fp32 fast argmax + fp64
// rescue of near-ties) but:
//  - argmax_fast: __launch_bounds__(256,2) so qr[128] stays in VGPRs (R2's (256,3)
//    capped VGPR at 76 -> q re-loaded from memory inside the k-loop -> 5x slowdown)
//  - EPS 1e-2 -> 2e-3 (fp32 gap error <= ~4e-4; 5x margin), smaller worklist
//  - prep kernels: 4-way unrolled independent fp64 accumulator chains (were
//    latency-bound on a 128-deep dependent chain)

#define MM   4
#define KC   256
#define DM   128
#define HW   4096   // h*w
#define NTOT 16
#define HH   64
#define WW_  64
#define EPS  2e-3f
#define WL_CAP 65536

// ---- Kernel 1: A[m][e][d] = sum_c wk[m][c][e] * wq[m][c][d]  (fp64) ----
__global__ __launch_bounds__(128) void a_kernel(const float* __restrict__ wk,
                                                const float* __restrict__ wq,
                                                double* __restrict__ A) {
    int me = blockIdx.x;           // m*128 + e
    int d  = threadIdx.x;
    int m  = me >> 7;
    int e  = me & 127;
    const float* wkm = wk + (size_t)m * DM * DM + e;       // wk[m][c][e], stride DM
    const float* wqm = wq + (size_t)m * DM * DM + d;       // wq[m][c][d], stride DM
    double s0 = 0.0, s1 = 0.0, s2 = 0.0, s3 = 0.0;
#pragma unroll 8
    for (int c = 0; c < DM; c += 4) {
        s0 = fma((double)wkm[(size_t)(c+0) * DM], (double)wqm[(size_t)(c+0) * DM], s0);
        s1 = fma((double)wkm[(size_t)(c+1) * DM], (double)wqm[(size_t)(c+1) * DM], s1);
        s2 = fma((double)wkm[(size_t)(c+2) * DM], (double)wqm[(size_t)(c+2) * DM], s2);
        s3 = fma((double)wkm[(size_t)(c+3) * DM], (double)wqm[(size_t)(c+3) * DM], s3);
    }
    A[(size_t)me * DM + d] = (s0 + s1) + (s2 + s3);
}

// ---- Kernel 2: keff[m][k][d] = sum_e cb[m][k][e] * A[m][e][d]  (fp64 + fp32 copy) ----
__global__ __launch_bounds__(128) void keff_kernel(const float* __restrict__ cb,
                                                   const double* __restrict__ A,
                                                   double* __restrict__ keffd,
                                                   float* __restrict__ keff32) {
    int mk = blockIdx.x;           // m*256 + k
    int d  = threadIdx.x;
    int m  = mk >> 8;
    const float*  cbr = cb + (size_t)mk * DM;              // cb[m][k][*]
    const double* Am  = A + (size_t)m * DM * DM + d;       // A[m][e][d], stride DM
    double s0 = 0.0, s1 = 0.0, s2 = 0.0, s3 = 0.0;
#pragma unroll 8
    for (int e = 0; e < DM; e += 4) {
        s0 = fma((double)cbr[e+0], Am[(size_t)(e+0) * DM], s0);
        s1 = fma((double)cbr[e+1], Am[(size_t)(e+1) * DM], s1);
        s2 = fma((double)cbr[e+2], Am[(size_t)(e+2) * DM], s2);
        s3 = fma((double)cbr[e+3], Am[(size_t)(e+3) * DM], s3);
    }
    double s = (s0 + s1) + (s2 + s3);
    keffd[(size_t)mk * DM + d]  = s;
    keff32[(size_t)mk * DM + d] = (float)s;
}

// ---- Kernel 3: fp32 argmax with near-tie detection ----
// block = 256: w = tid&63 (coalesced lanes), m = tid>>6 (one wave per group)
// launch_bounds(256,2): VGPR budget 256 so qr[128] stays resident.
__global__ __launch_bounds__(256, 2) void argmax_fast(const float* __restrict__ latent,
                                                      const float* __restrict__ keff32,
                                                      int* __restrict__ out,
                                                      int* __restrict__ wl_cnt,
                                                      int* __restrict__ wl) {
    int b   = blockIdx.x;            // n*64 + h
    int n   = b >> 6;
    int h   = b & 63;
    int tid = threadIdx.x;
    int w   = tid & 63;
    int m   = tid >> 6;
    int mu  = __builtin_amdgcn_readfirstlane(m);   // wave-uniform -> scalar keff loads

    const float* lp = latent + ((size_t)n * 512 + (size_t)mu * DM) * HW + (size_t)h * WW_ + w;
    float qr[DM];
#pragma unroll
    for (int d = 0; d < DM; ++d) qr[d] = lp[(size_t)d * HW];

    const float* kp = keff32 + (size_t)mu * KC * DM;

    float bestv = -3.0e38f, secondv = -3.0e38f;
    int   best  = 0;
    for (int k = 0; k < KC; k += 4) {
        const float* r0 = kp + (size_t)k * DM;
        const float* r1 = r0 + DM;
        const float* r2 = r1 + DM;
        const float* r3 = r2 + DM;
        float s0 = 0.f, s1 = 0.f, s2 = 0.f, s3 = 0.f;
#pragma unroll
        for (int d = 0; d < DM; ++d) {
            float qd = qr[d];
            s0 = fmaf(qd, r0[d], s0);
            s1 = fmaf(qd, r1[d], s1);
            s2 = fmaf(qd, r2[d], s2);
            s3 = fmaf(qd, r3[d], s3);
        }
        // ascending k + strict '>' == first-occurrence argmax; track runner-up
        if (s0 > bestv) { secondv = bestv; bestv = s0; best = k;     } else if (s0 > secondv) secondv = s0;
        if (s1 > bestv) { secondv = bestv; bestv = s1; best = k + 1; } else if (s1 > secondv) secondv = s1;
        if (s2 > bestv) { secondv = bestv; bestv = s2; best = k + 2; } else if (s2 > secondv) secondv = s2;
        if (s3 > bestv) { secondv = bestv; bestv = s3; best = k + 3; } else if (s3 > secondv) secondv = s3;
    }

    int pix = ((b * WW_ + w) * MM) + m;   // n,h,w,m flat index
    out[pix] = best;

    if (bestv - secondv < EPS) {
        int slot = atomicAdd(wl_cnt, 1);
        if (slot < WL_CAP) wl[slot] = pix;
    }
}

// ---- Kernel 4: fp64 rescue of flagged pixel-groups ----
__global__ __launch_bounds__(256) void rescue_kernel(const float* __restrict__ latent,
                                                     const double* __restrict__ keffd,
                                                     const int* __restrict__ wl_cnt,
                                                     const int* __restrict__ wl,
                                                     int* __restrict__ out) {
    __shared__ double svals[256];
    __shared__ int    sidx[256];
    int cnt = *wl_cnt;
    if (cnt > WL_CAP) cnt = WL_CAP;
    int t = threadIdx.x;
    for (int i = blockIdx.x; i < cnt; i += gridDim.x) {
        int pix = wl[i];
        int m   = pix & 3;
        int rem = pix >> 2;          // (n*64+h)*64 + w
        int w   = rem & 63;
        int bh  = rem >> 6;          // n*64+h
        int n   = bh >> 6;
        int h   = bh & 63;
        const float*  lp = latent + ((size_t)n * 512 + (size_t)m * DM) * HW + (size_t)h * WW_ + w;
        const double* kr = keffd + ((size_t)m * KC + t) * DM;
        double s = 0.0;
        for (int d = 0; d < DM; ++d)
            s = fma((double)lp[(size_t)d * HW], kr[d], s);
        svals[t] = s;
        sidx[t]  = t;
        __syncthreads();
        for (int stp = 128; stp > 0; stp >>= 1) {
            if (t < stp) {
                double vo = svals[t + stp], vm = svals[t];
                int io = sidx[t + stp], im = sidx[t];
                if (vo > vm || (vo == vm && io < im)) { svals[t] = vo; sidx[t] = io; }
            }
            __syncthreads();
        }
        if (t == 0) out[pix] = sidx[0];
        __syncthreads();
    }
}

extern "C" void kernel_launch(void* const* d_in, const int* in_sizes, int n_in,
                              void* d_out, int out_size, void* d_ws, size_t ws_size,
                              hipStream_t stream) {
    const float* latent = (const float*)d_in[0];   // [16,512,64,64]
    const float* cb     = (const float*)d_in[1];   // [4,256,128]
    const float* wq     = (const float*)d_in[2];   // [4,128,128]
    const float* wk     = (const float*)d_in[3];   // [4,128,128]
    int* out = (int*)d_out;                        // 262144 code indices (int32)

    // workspace layout
    char* ws = (char*)d_ws;
    double* A       = (double*)ws;                          ws += (size_t)MM * DM * DM * sizeof(double);   // 512 KB
    double* keffd   = (double*)ws;                          ws += (size_t)MM * KC * DM * sizeof(double);   // 1 MB
    float*  keff32  = (float*)ws;                           ws += (size_t)MM * KC * DM * sizeof(float);    // 512 KB
    int*    wl_cnt  = (int*)ws;                             ws += 256;
    int*    wl      = (int*)ws;                              // WL_CAP * 4 = 256 KB

    hipMemsetAsync(wl_cnt, 0, sizeof(int), stream);
    a_kernel<<<MM * DM, 128, 0, stream>>>(wk, wq, A);
    keff_kernel<<<MM * KC, 128, 0, stream>>>(cb, A, keffd, keff32);
    argmax_fast<<<NTOT * HH, 256, 0, stream>>>(latent, keff32, out, wl_cnt, wl);
    rescue_kernel<<<256, 256, 0, stream>>>(latent, keffd, wl_cnt, wl, out);
}